// Round 7
// baseline (261.818 us; speedup 1.0000x reference)
//
#include <hip/hip_runtime.h>

typedef unsigned short u16;
typedef unsigned int u32;
typedef __attribute__((ext_vector_type(8))) short bf16x8;
typedef __attribute__((ext_vector_type(4))) float f32x4;

#define NPTS 2048
#define CFEAT 256
#define NS 32
#define MTOT 262144           // 4*2048*32
#define GRID1 2048            // MTOT/128
#define INV_N (1.0f/262144.0f)
#define ASTR 40               // padded LDS A stride (u16)
#define YSTR 260              // epilogue scatter stride (u16): conflict-free scalar writes

__device__ __forceinline__ float bf2f(u16 u) {
    union { u32 i; float f; } v; v.i = ((u32)u) << 16; return v.f;
}
__device__ __forceinline__ u16 f2bf(float f) {
    union { float f; u32 i; } v; v.f = f;
    u32 i = v.i;
    return (u16)((i + 0x7fffu + ((i >> 16) & 1u)) >> 16);
}

// async 1 KB wave copy: lds base wave-uniform, DMA lands at base + lane*16B
__device__ __forceinline__ void stage1k(u16* lds, const u16* g, int lane) {
    __builtin_amdgcn_global_load_lds((const __attribute__((address_space(1))) void*)(g + lane * 8),
                                     (__attribute__((address_space(3))) void*)lds, 16, 0, 0);
}

// ---------------- prep: LINEAR K-tiled weights. WpT[ks][n(256)][kc(32)] ----------------
__global__ __launch_bounds__(256) void prep_k(const float* __restrict__ W1, const float* __restrict__ W2,
                                              u16* __restrict__ Wp1T, u16* __restrict__ Wp2T) {
    int o = blockIdx.x, t = threadIdx.x;
    int ks = t >> 5, kc = t & 31;
    Wp1T[(ks * 256 + o) * 32 + kc] = f2bf(W1[o * 259 + 3 + t]);
    Wp2T[(ks * 256 + o) * 32 + kc] = f2bf(W2[o * 256 + t]);
    if (t < 32) Wp1T[(8 * 256 + o) * 32 + t] = (t < 3) ? f2bf(W1[o * 259 + t]) : (u16)0;
}

// ---------------- cylinder query: wave per point, ballot compaction ----------------
__global__ __launch_bounds__(256) void query_k(const float* __restrict__ xyz, const float* __restrict__ rot,
                                               int* __restrict__ idx) {
    int pid = blockIdx.x * 4 + (threadIdx.x >> 6);
    int lane = threadIdx.x & 63;
    int b = pid >> 11, p = pid & 2047;
    const float* xb = xyz + (size_t)b * NPTS * 3;
    float px = xb[p * 3 + 0], py = xb[p * 3 + 1], pz = xb[p * 3 + 2];
    const float* rp = rot + (size_t)pid * 9;
    float r00 = rp[0], r01 = rp[1], r02 = rp[2];
    float r10 = rp[3], r11 = rp[4], r12 = rp[5];
    float r20 = rp[6], r21 = rp[7], r22 = rp[8];
    int cnt = 0, first = 0;
    for (int n0 = 0; n0 < NPTS && cnt < NS; n0 += 64) {
        int n = n0 + lane;
        float dx = __fsub_rn(xb[n * 3 + 0], px);
        float dy = __fsub_rn(xb[n * 3 + 1], py);
        float dz = __fsub_rn(xb[n * 3 + 2], pz);
        float a0 = __fadd_rn(__fadd_rn(__fmul_rn(r00, dx), __fmul_rn(r01, dy)), __fmul_rn(r02, dz));
        float a1 = __fadd_rn(__fadd_rn(__fmul_rn(r10, dx), __fmul_rn(r11, dy)), __fmul_rn(r12, dz));
        float a2 = __fadd_rn(__fadd_rn(__fmul_rn(r20, dx), __fmul_rn(r21, dy)), __fmul_rn(r22, dz));
        float t2 = __fadd_rn(__fmul_rn(a1, a1), __fmul_rn(a2, a2));
        bool valid = (t2 < 0.0025f) && (a0 > -0.02f) && (a0 < 0.04f);
        unsigned long long bal = __ballot(valid);
        if (cnt == 0 && bal) first = n0 + __builtin_ctzll(bal);
        int rank = __builtin_popcountll(bal & ((1ull << lane) - 1ull));
        int slot = cnt + rank;
        if (valid && slot < NS) idx[(size_t)pid * NS + slot] = n;
        cnt += __builtin_popcountll(bal);
    }
    int filled = cnt < NS ? cnt : NS;
    if (lane >= filled && lane < NS) idx[(size_t)pid * NS + lane] = (cnt > 0) ? first : 0;
}

// ---------------- features (B,C,N) fp32 -> featT (B,N,C) bf16 ----------------
__global__ __launch_bounds__(256) void featT_k(const float* __restrict__ feat, u16* __restrict__ featT) {
    __shared__ float sm[32 * 33];
    int b = blockIdx.z;
    int n0 = blockIdx.x * 32, c0 = blockIdx.y * 32;
    int t = threadIdx.x, x = t & 31, y = t >> 5;
    #pragma unroll
    for (int rr = 0; rr < 4; rr++) {
        int c = c0 + y + rr * 8;
        sm[(y + rr * 8) * 33 + x] = feat[((size_t)(b * CFEAT + c)) * NPTS + n0 + x];
    }
    __syncthreads();
    #pragma unroll
    for (int rr = 0; rr < 4; rr++) {
        int n = n0 + y + rr * 8;
        featT[((size_t)(b * NPTS + n)) * CFEAT + c0 + x] = f2bf(sm[x * 33 + (y + rr * 8)]);
    }
}

// ---------------- pass 1: 128x256 GEMM1 (main loop = round-6 proven) ----------------
// epilogue: C-frags -> LDS (stride 260) -> row-major K-tiled y1t + stats1. gxyz computed in-block.
__global__ __launch_bounds__(256, 2) void gemm1_k(
    const float* __restrict__ xyz, const float* __restrict__ rot,
    const u16* __restrict__ featT, const int* __restrict__ idx,
    const u16* __restrict__ Wp1T, float* __restrict__ psum, float* __restrict__ psq,
    u16* __restrict__ y1t)
{
    __shared__ __attribute__((aligned(16))) u16 smem[26624];  // As 2x5120 | Bs 2x8192 ; epi: y1s 64x260
    __shared__ int rowb[128];
    __shared__ uint2 gxs[128];
    u16* As = smem;
    u16* Bs = smem + 10240;

    const int tid = threadIdx.x;
    const int lane = tid & 63, wave = tid >> 6;
    const int quad = lane >> 4, tl = lane & 15;
    const int wm = (wave & 1) * 64, wn = (wave >> 1) * 128;
    const int bx = blockIdx.x;
    const int m0 = bx * 128;
    const int srow = tid >> 1, shalf = tid & 1;

    if (tid < 128) {
        int m = m0 + tid;
        int b = m >> 16, p = (m >> 5) & 2047, gi = idx[m];
        rowb[tid] = b * (NPTS * CFEAT) + gi * CFEAT;
        const float* xb = xyz + (size_t)b * NPTS * 3;
        float dx = (xb[gi * 3 + 0] - xb[p * 3 + 0]) * 20.0f;
        float dy = (xb[gi * 3 + 1] - xb[p * 3 + 1]) * 20.0f;
        float dz = (xb[gi * 3 + 2] - xb[p * 3 + 2]) * 20.0f;
        const float* rp = rot + (size_t)(m >> 5) * 9;
        float g0 = dx * rp[0] + dy * rp[3] + dz * rp[6];
        float g1 = dx * rp[1] + dy * rp[4] + dz * rp[7];
        float g2 = dx * rp[2] + dy * rp[5] + dz * rp[8];
        gxs[tid] = make_uint2((u32)f2bf(g0) | ((u32)f2bf(g1) << 16), (u32)f2bf(g2));
    }
    __syncthreads();

    // prologue: stage chunk 0 into buffer 0
    {
        const u16* p = featT + rowb[srow] + shalf * 16;
        *(uint4*)(As + srow * ASTR + shalf * 16) = *(const uint4*)p;
        *(uint4*)(As + srow * ASTR + shalf * 16 + 8) = *(const uint4*)(p + 8);
    }
    #pragma unroll
    for (int c = 0; c < 4; c++)
        stage1k(Bs + wave * 2048 + c * 512, Wp1T + wave * 2048 + c * 512, lane);

    f32x4 acc[4][8];
    #pragma unroll
    for (int i = 0; i < 4; i++)
        #pragma unroll
        for (int j = 0; j < 8; j++) acc[i][j] = (f32x4){0.f, 0.f, 0.f, 0.f};

    for (int ks = 0; ks < 9; ks++) {
        __syncthreads();
        const u16* Ab = As + (ks & 1) * 5120;
        const u16* Bb = Bs + (ks & 1) * 8192;
        bf16x8 af[4], bv[8];
        #pragma unroll
        for (int i = 0; i < 4; i++)
            af[i] = *(const bf16x8*)(Ab + (wm + i * 16 + tl) * ASTR + quad * 8);
        #pragma unroll
        for (int j = 0; j < 8; j++)
            bv[j] = *(const bf16x8*)(Bb + (wn + j * 16 + tl) * 32 + quad * 8);
        if (ks < 8) {
            u16* An = As + ((ks + 1) & 1) * 5120;
            u16* Bn = Bs + ((ks + 1) & 1) * 8192;
            const u16* gsrc = Wp1T + (ks + 1) * 8192;
            #pragma unroll
            for (int c = 0; c < 4; c++)
                stage1k(Bn + wave * 2048 + c * 512, gsrc + wave * 2048 + c * 512, lane);
            uint4 v0, v1;
            if (ks + 1 < 8) {
                const u16* p = featT + rowb[srow] + (ks + 1) * 32 + shalf * 16;
                v0 = *(const uint4*)p; v1 = *(const uint4*)(p + 8);
            } else {       // xyz chunk: row = [g0,g1,g2,0,...,0]
                v0 = make_uint4(0, 0, 0, 0); v1 = v0;
                if (shalf == 0) {
                    uint2 g2 = gxs[srow];
                    v0.x = g2.x; v0.y = g2.y;
                }
            }
            *(uint4*)(An + srow * ASTR + shalf * 16) = v0;
            *(uint4*)(An + srow * ASTR + shalf * 16 + 8) = v1;
        }
        #pragma unroll
        for (int j = 0; j < 8; j++)
            #pragma unroll
            for (int i = 0; i < 4; i++)
                acc[i][j] = __builtin_amdgcn_mfma_f32_16x16x32_bf16(af[i], bv[j], acc[i][j], 0, 0, 0);
    }

    // ---- epilogue: two 64-row rounds: scatter C-frags to LDS + stats, then coalesced y1t store ----
    u16* y1s = smem;                     // 64 x 260 u16 (reuses As/Bs space)
    const int lrow = tid >> 2, c4 = tid & 3;
    #pragma unroll
    for (int r = 0; r < 2; r++) {
        __syncthreads();                 // main-loop / previous-round readers done
        if ((wave & 1) == r) {
            const int mb = bx * 2 + r;
            #pragma unroll
            for (int j = 0; j < 8; j++) {
                int col = wn + j * 16 + tl;
                float s = 0.f, q2 = 0.f;
                #pragma unroll
                for (int i = 0; i < 4; i++)
                    #pragma unroll
                    for (int rr = 0; rr < 4; rr++) {
                        u16 h = f2bf(acc[i][j][rr]);
                        y1s[(i * 16 + quad * 4 + rr) * YSTR + col] = h;
                        float v = bf2f(h); s += v; q2 += v * v;
                    }
                s += __shfl_xor(s, 16); s += __shfl_xor(s, 32);
                q2 += __shfl_xor(q2, 16); q2 += __shfl_xor(q2, 32);
                if (quad == 0) {
                    psum[(size_t)mb * 256 + col] = s;
                    psq[(size_t)mb * 256 + col] = q2;
                }
            }
        }
        __syncthreads();
        #pragma unroll
        for (int ks = 0; ks < 8; ks++) {
            const u16* sp = y1s + lrow * YSTR + ks * 32 + c4 * 8;
            uint2 a0 = *(const uint2*)sp;
            uint2 a1 = *(const uint2*)(sp + 4);
            *(uint4*)(y1t + (((size_t)bx * 8 + ks) * 128 + r * 64 + lrow) * 32 + c4 * 8) =
                make_uint4(a0.x, a0.y, a1.x, a1.y);
        }
    }
}

// ---------------- pass 2: 128x256 GEMM2. A: y1t rows, norm+relu at staging. B: DMA dbuf. ----------------
__global__ __launch_bounds__(256, 2) void gemm2_k(
    const u16* __restrict__ y1t, const u16* __restrict__ Wp2T, const float* __restrict__ ab1,
    float* __restrict__ psum, float* __restrict__ psq,
    float* __restrict__ ymax, float* __restrict__ ymin)
{
    __shared__ __attribute__((aligned(16))) u16 smem[26624];  // As 2x5120 | Bs 2x8192
    __shared__ float coef[512];
    u16* As = smem;
    u16* Bs = smem + 10240;

    const int tid = threadIdx.x;
    const int lane = tid & 63, wave = tid >> 6;
    const int quad = lane >> 4, tl = lane & 15;
    const int wm = (wave & 1) * 64, wn = (wave >> 1) * 128;
    const int bx = blockIdx.x;
    const int srow = tid >> 1, shalf = tid & 1;
    const u16* Abase = y1t + (size_t)bx * 32768;

    ((float2*)coef)[tid] = ((const float2*)ab1)[tid];
    __syncthreads();

    // stage A chunk ks (normalize+relu in flight) into An
    auto stageA = [&](int ks, u16* An) {
        const u16* pp = Abase + (ks * 128 + srow) * 32 + shalf * 16;
        uint4 v0 = *(const uint4*)pp, v1 = *(const uint4*)(pp + 8);
        const float4* ca = (const float4*)(coef + ks * 32 + shalf * 16);
        const float4* cb = (const float4*)(coef + 256 + ks * 32 + shalf * 16);
        u32 w[8] = {v0.x, v0.y, v0.z, v0.w, v1.x, v1.y, v1.z, v1.w};
        u32 o[8];
        #pragma unroll
        for (int g = 0; g < 4; g++) {
            float4 a4 = ca[g], b4 = cb[g];
            float f0 = fmaxf(fmaf(bf2f((u16)(w[2*g]   & 0xffff)), a4.x, b4.x), 0.f);
            float f1 = fmaxf(fmaf(bf2f((u16)(w[2*g]   >> 16)),    a4.y, b4.y), 0.f);
            float f2 = fmaxf(fmaf(bf2f((u16)(w[2*g+1] & 0xffff)), a4.z, b4.z), 0.f);
            float f3 = fmaxf(fmaf(bf2f((u16)(w[2*g+1] >> 16)),    a4.w, b4.w), 0.f);
            o[2*g]   = (u32)f2bf(f0) | ((u32)f2bf(f1) << 16);
            o[2*g+1] = (u32)f2bf(f2) | ((u32)f2bf(f3) << 16);
        }
        *(uint4*)(An + srow * ASTR + shalf * 16)     = make_uint4(o[0], o[1], o[2], o[3]);
        *(uint4*)(An + srow * ASTR + shalf * 16 + 8) = make_uint4(o[4], o[5], o[6], o[7]);
    };

    stageA(0, As);
    #pragma unroll
    for (int c = 0; c < 4; c++)
        stage1k(Bs + wave * 2048 + c * 512, Wp2T + wave * 2048 + c * 512, lane);

    f32x4 acc[4][8];
    #pragma unroll
    for (int i = 0; i < 4; i++)
        #pragma unroll
        for (int j = 0; j < 8; j++) acc[i][j] = (f32x4){0.f, 0.f, 0.f, 0.f};

    for (int ks = 0; ks < 8; ks++) {
        __syncthreads();
        const u16* Ab = As + (ks & 1) * 5120;
        const u16* Bb = Bs + (ks & 1) * 8192;
        bf16x8 af[4], bv[8];
        #pragma unroll
        for (int i = 0; i < 4; i++)
            af[i] = *(const bf16x8*)(Ab + (wm + i * 16 + tl) * ASTR + quad * 8);
        #pragma unroll
        for (int j = 0; j < 8; j++)
            bv[j] = *(const bf16x8*)(Bb + (wn + j * 16 + tl) * 32 + quad * 8);
        if (ks < 7) {
            stageA(ks + 1, As + ((ks + 1) & 1) * 5120);
            const u16* gsrc = Wp2T + (ks + 1) * 8192;
            u16* Bn = Bs + ((ks + 1) & 1) * 8192;
            #pragma unroll
            for (int c = 0; c < 4; c++)
                stage1k(Bn + wave * 2048 + c * 512, gsrc + wave * 2048 + c * 512, lane);
        }
        #pragma unroll
        for (int j = 0; j < 8; j++)
            #pragma unroll
            for (int i = 0; i < 4; i++)
                acc[i][j] = __builtin_amdgcn_mfma_f32_16x16x32_bf16(af[i], bv[j], acc[i][j], 0, 0, 0);
    }

    // ---- epilogue: stats2 + per-pid max/min (pid = bx*4 + (wave&1)*2 + (i>=2)) ----
    #pragma unroll
    for (int j = 0; j < 8; j++) {
        int col = wn + j * 16 + tl;
        float s = 0.f, q2 = 0.f;
        float mx0 = -3.0e38f, mn0 = 3.0e38f, mx1 = -3.0e38f, mn1 = 3.0e38f;
        #pragma unroll
        for (int i = 0; i < 4; i++)
            #pragma unroll
            for (int rr = 0; rr < 4; rr++) {
                float v = acc[i][j][rr];
                s += v; q2 += v * v;
                if (i < 2) { mx0 = fmaxf(mx0, v); mn0 = fminf(mn0, v); }
                else       { mx1 = fmaxf(mx1, v); mn1 = fminf(mn1, v); }
            }
        s += __shfl_xor(s, 16); s += __shfl_xor(s, 32);
        q2 += __shfl_xor(q2, 16); q2 += __shfl_xor(q2, 32);
        mx0 = fmaxf(mx0, __shfl_xor(mx0, 16)); mx0 = fmaxf(mx0, __shfl_xor(mx0, 32));
        mn0 = fminf(mn0, __shfl_xor(mn0, 16)); mn0 = fminf(mn0, __shfl_xor(mn0, 32));
        mx1 = fmaxf(mx1, __shfl_xor(mx1, 16)); mx1 = fmaxf(mx1, __shfl_xor(mx1, 32));
        mn1 = fminf(mn1, __shfl_xor(mn1, 16)); mn1 = fminf(mn1, __shfl_xor(mn1, 32));
        if (quad == 0) {
            int mb = bx * 2 + (wave & 1);
            psum[(size_t)mb * 256 + col] = s;
            psq[(size_t)mb * 256 + col] = q2;
            size_t p0 = ((size_t)bx * 4 + (wave & 1) * 2) * 256 + col;
            ymax[p0] = mx0; ymin[p0] = mn0;
            ymax[p0 + 256] = mx1; ymin[p0 + 256] = mn1;
        }
    }
}

// ---------------- reduce partials [4096][256] -> per-channel (a,b) ----------------
__global__ __launch_bounds__(256) void reduce_k(const float* __restrict__ psum, const float* __restrict__ psq,
                                                const float* __restrict__ gamma, const float* __restrict__ beta,
                                                float* __restrict__ ab) {
    __shared__ float red[8];
    int c = blockIdx.x, t = threadIdx.x;
    float s = 0.f, q = 0.f;
    for (int k = t; k < 4096; k += 256) { s += psum[(size_t)k * 256 + c]; q += psq[(size_t)k * 256 + c]; }
    #pragma unroll
    for (int o = 32; o >= 1; o >>= 1) { s += __shfl_xor(s, o); q += __shfl_xor(q, o); }
    int lane = t & 63, w = t >> 6;
    if (lane == 0) { red[w] = s; red[4 + w] = q; }
    __syncthreads();
    if (t == 0) {
        float S = red[0] + red[1] + red[2] + red[3];
        float Q = red[4] + red[5] + red[6] + red[7];
        float mu = S * INV_N;
        float var = Q * INV_N - mu * mu;
        float a = gamma[c] * rsqrtf(var + 1e-5f);
        ab[c] = a;
        ab[256 + c] = beta[c] - mu * a;
    }
}

// ---------------- final: relu(a*(a>=0?max:min)+b), transpose -> (B,O,N) ----------------
__global__ __launch_bounds__(256) void final_k(const float* __restrict__ ymax, const float* __restrict__ ymin,
                                               const float* __restrict__ ab, float* __restrict__ out) {
    __shared__ float sm[32 * 33];
    int b = blockIdx.z;
    int n0 = blockIdx.x * 32, o0 = blockIdx.y * 32;
    int t = threadIdx.x, x = t & 31, y = t >> 5;
    #pragma unroll
    for (int rr = 0; rr < 4; rr++) {
        int n = n0 + y + rr * 8;
        int o = o0 + x;
        float a = ab[o], bb = ab[256 + o];
        size_t p = (size_t)(b * NPTS + n) * 256 + o;
        float v = (a >= 0.f) ? ymax[p] : ymin[p];
        sm[(y + rr * 8) * 33 + x] = fmaxf(fmaf(v, a, bb), 0.f);
    }
    __syncthreads();
    #pragma unroll
    for (int rr = 0; rr < 4; rr++)
        out[((size_t)(b * 256 + o0 + y + rr * 8)) * NPTS + n0 + x] = sm[x * 33 + (y + rr * 8)];
}

extern "C" void kernel_launch(void* const* d_in, const int* in_sizes, int n_in,
                              void* d_out, int out_size, void* d_ws, size_t ws_size,
                              hipStream_t stream) {
    const float* xyz    = (const float*)d_in[0];
    const float* feat   = (const float*)d_in[1];
    const float* rot    = (const float*)d_in[2];
    const float* W1     = (const float*)d_in[3];
    const float* gamma1 = (const float*)d_in[4];
    const float* beta1  = (const float*)d_in[5];
    const float* W2     = (const float*)d_in[6];
    const float* gamma2 = (const float*)d_in[7];
    const float* beta2  = (const float*)d_in[8];
    float* out = (float*)d_out;

    char* ws = (char*)d_ws;
    u16*   featT = (u16*)(ws + 0);           //  4,194,304
    int*   idx   = (int*)(ws + 4194304);     //  1,048,576
    u16*   Wp1T  = (u16*)(ws + 7340032);     //    147,456
    u16*   Wp2T  = (u16*)(ws + 7487488);     //    131,072
    float* ab1   = (float*)(ws + 7618560);   //      2,048
    float* ab2   = (float*)(ws + 7620608);   //      2,048
    float* psum  = (float*)(ws + 7622656);   //  4,194,304
    float* psq   = (float*)(ws + 11816960);  //  4,194,304
    float* ymax  = (float*)(ws + 16011264);  //  8,388,608
    float* ymin  = (float*)(ws + 24399872);  //  8,388,608
    u16*   y1t   = (u16*)(ws + 32788480);    // 134,217,728 (row-major K-tiled [bx][ks][128][32])

    prep_k<<<256, 256, 0, stream>>>(W1, W2, Wp1T, Wp2T);
    query_k<<<2048, 256, 0, stream>>>(xyz, rot, idx);
    featT_k<<<dim3(64, 8, 4), 256, 0, stream>>>(feat, featT);

    gemm1_k<<<GRID1, 256, 0, stream>>>(xyz, rot, featT, idx, Wp1T, psum, psq, y1t);
    reduce_k<<<256, 256, 0, stream>>>(psum, psq, gamma1, beta1, ab1);
    gemm2_k<<<GRID1, 256, 0, stream>>>(y1t, Wp2T, ab1, psum, psq, ymax, ymin);
    reduce_k<<<256, 256, 0, stream>>>(psum, psq, gamma2, beta2, ab2);
    final_k<<<dim3(64, 8, 4), 256, 0, stream>>>(ymax, ymin, ab2, out);
}